// Round 24
// baseline (42.098 us; speedup 1.0000x reference)
//
#include <hip/hip_runtime.h>

#define N_Q   50000
#define N_S   50000
#define M_NB  32
#define K_PTS 15
#define CIN   64
#define COUT  64
#define THR   0.0101f   // ||nb||^2 bound for any w>0 (exact: 0.009901)
#define NSEG  25000     // one worklist segment per scan wave (12500 blk x 2)
#define WL_OFF 131072   // counts[25000] ints (100KB) then int2 worklist

// ---------------- phase 1: far skeleton + close-point emit ----------------
// R19's proven scan shape: one wave per TWO query points (A = lanes 0-31,
// B = lanes 32-63), scalar query loads. Writes BOTH rows as zeros (phase 2
// overwrites close rows), and emits 0-2 close point ids into the wave's
// PRIVATE worklist slot — counts written unconditionally, no atomics, no
// zeroing pass, no LDS, no syncthreads.
__global__ __launch_bounds__(128) void scan_emit(
    const float* __restrict__ query,     // [N,3]
    const float* __restrict__ support,   // [N0,3]
    const int*   __restrict__ neighbors, // [N,M]
    int*         __restrict__ counts,    // [NSEG]
    int2*        __restrict__ worklist,  // [NSEG]
    float4*      __restrict__ out4)      // [N*COUT/4]
{
    const int tid  = threadIdx.x;
    const int wv   = __builtin_amdgcn_readfirstlane(tid >> 6);  // 0..1
    const int lane = tid & 63;
    const int base = blockIdx.x * 4 + wv * 2;      // grid = N_Q/4 exactly
    const int wid  = blockIdx.x * 2 + wv;          // segment id
    const int h    = lane >> 5;
    const int n    = base + h;
    const int m    = lane & 31;

    // scalar (SMEM) query loads: uniform addresses
    const float qxA = query[(base + 0) * 3 + 0];
    const float qyA = query[(base + 0) * 3 + 1];
    const float qzA = query[(base + 0) * 3 + 2];
    const float qxB = query[(base + 1) * 3 + 0];
    const float qyB = query[(base + 1) * 3 + 1];
    const float qzB = query[(base + 1) * 3 + 2];
    const float qx = h ? qxB : qxA;
    const float qy = h ? qyB : qyA;
    const float qz = h ? qzB : qzA;

    const int idx = neighbors[n * M_NB + m];       // coalesced (2 rows/wave)

    float nn = 1e30f;
    if (idx < N_S) {                               // idx==N_S: shadow, w==0
        const float dx = support[idx * 3 + 0] - qx;
        const float dy = support[idx * 3 + 1] - qy;
        const float dz = support[idx * 3 + 2] - qz;
        nn = dx * dx + dy * dy + dz * dz;
    }

    // zero both output rows (phase 2 overwrites close rows; stream-ordered)
    if (lane < 32)
        out4[(size_t)base * (COUT / 4) + lane] = make_float4(0.f, 0.f, 0.f, 0.f);

    const unsigned long long cb = __ballot(nn < THR);
    const int cA = ((unsigned)(cb & 0xffffffffull)) != 0;
    const int cB = ((unsigned)(cb >> 32)) != 0;
    if (lane == 0) {
        counts[wid] = cA + cB;                     // written EVERY call
        if (cA + cB)
            worklist[wid] = make_int2(cA ? base : base + 1, base + 1);
    }
}

// ---------------- phase 2: close points at full parallelism ----------------
// 8192 waves grid-stride the 25000 segments (~6400 close points total, ~1 per
// wave). Per point: R13/R14's proven close path — lanes 0-31 gather+distance;
// per active k: racc (c=lane, saddr x loads) then wide GEMV (lane owns quad
// og=(lane&15)*4, c-subset cg=lane>>4; 16 dwordx4, shfl_xor(16,32) reduce);
// lanes 0-15 overwrite the pre-zeroed row. One wave owns a point: no atomics.
__global__ __launch_bounds__(256) void close_kernel(
    const float* __restrict__ query,
    const float* __restrict__ support,
    const int*   __restrict__ neighbors,
    const float* __restrict__ x,         // [N0,CIN]
    const float* __restrict__ kpts,      // [K,3]
    const float* __restrict__ weight,    // [K,CIN,COUT]
    const int*   __restrict__ counts,
    const int2*  __restrict__ worklist,
    float*       __restrict__ out)       // [N,COUT]
{
    __shared__ float s_kx[K_PTS], s_ky[K_PTS], s_kz[K_PTS], s_kk[K_PTS];
    __shared__ float s_bc[4][CIN];

    const int tid = threadIdx.x;
    if (tid < K_PTS) {
        float kx = kpts[tid * 3 + 0];
        float ky = kpts[tid * 3 + 1];
        float kz = kpts[tid * 3 + 2];
        s_kx[tid] = kx; s_ky[tid] = ky; s_kz[tid] = kz;
        s_kk[tid] = kx * kx + ky * ky + kz * kz;   // same 3-term fp32 sum as ref
    }
    __syncthreads();

    const int wv   = tid >> 6;                     // 0..3
    const int lane = tid & 63;
    const int wid  = blockIdx.x * 4 + wv;
    const int nw   = gridDim.x * 4;
    const int og   = (lane & 15) * 4;
    const int cg   = lane >> 4;

    for (int seg = wid; seg < NSEG; seg += nw) {
        const int cnt = counts[seg];               // wave-uniform load
        if (!cnt) continue;                        // ~77% of segments
        const int2 wl = worklist[seg];

        for (int i = 0; i < cnt; ++i) {
            const int n = __builtin_amdgcn_readfirstlane(i ? wl.y : wl.x);

            int idx = N_S;
            float dx = 0.f, dy = 0.f, dz = 0.f, nn = 1e30f;
            if (lane < 32) {
                idx = neighbors[n * M_NB + lane];
                if (idx < N_S) {
                    dx = support[idx * 3 + 0] - query[n * 3 + 0];  // q: s_load
                    dy = support[idx * 3 + 1] - query[n * 3 + 1];
                    dz = support[idx * 3 + 2] - query[n * 3 + 2];
                    nn = dx * dx + dy * dy + dz * dz;
                }
            }

            float4 tq = make_float4(0.f, 0.f, 0.f, 0.f);

            for (int k = 0; k < K_PTS; ++k) {
                float w = 0.f;
                if (nn < THR) {
                    float dot = dx * s_kx[k] + dy * s_ky[k] + dz * s_kz[k];
                    float sq  = fmaxf(nn - 2.f * dot + s_kk[k], 0.f);  // ref expn
                    if (sq < 0.0025f)               // sqrt(sq) < 0.05 => w > 0
                        w = 1.f - sqrtf(sq) * 20.f; // 1/0.05 == 20 exactly
                }
                unsigned em = (unsigned)__ballot(w > 0.f);  // lanes 0-31 only
                if (!em) continue;

                float racc = 0.f;
                do {
                    const int src = __builtin_ctz(em); em &= em - 1;
                    const float wsrc = __shfl(w, src);
                    const int   isrc = __builtin_amdgcn_readfirstlane(
                                           __shfl(idx, src));
                    racc = fmaf(wsrc, x[(size_t)isrc * CIN + lane], racc);
                } while (em);

                s_bc[wv][lane] = racc;
                asm volatile("" ::: "memory");
                const float* wq = weight + (size_t)k * CIN * COUT + cg * COUT + og;
                float4 a0 = make_float4(0.f, 0.f, 0.f, 0.f);
                float4 a1 = make_float4(0.f, 0.f, 0.f, 0.f);
                #pragma unroll
                for (int q = 0; q < 16; q += 2) {
                    const float4 v0 = *(const float4*)(wq + (q + 0) * 4 * COUT);
                    const float4 v1 = *(const float4*)(wq + (q + 1) * 4 * COUT);
                    const float xc0 = s_bc[wv][cg + 4 * q];
                    const float xc1 = s_bc[wv][cg + 4 * q + 4];
                    a0.x = fmaf(xc0, v0.x, a0.x); a0.y = fmaf(xc0, v0.y, a0.y);
                    a0.z = fmaf(xc0, v0.z, a0.z); a0.w = fmaf(xc0, v0.w, a0.w);
                    a1.x = fmaf(xc1, v1.x, a1.x); a1.y = fmaf(xc1, v1.y, a1.y);
                    a1.z = fmaf(xc1, v1.z, a1.z); a1.w = fmaf(xc1, v1.w, a1.w);
                }
                a0.x += a1.x; a0.y += a1.y; a0.z += a1.z; a0.w += a1.w;
                a0.x += __shfl_xor(a0.x, 16); a0.y += __shfl_xor(a0.y, 16);
                a0.z += __shfl_xor(a0.z, 16); a0.w += __shfl_xor(a0.w, 16);
                a0.x += __shfl_xor(a0.x, 32); a0.y += __shfl_xor(a0.y, 32);
                a0.z += __shfl_xor(a0.z, 32); a0.w += __shfl_xor(a0.w, 32);
                tq.x += a0.x; tq.y += a0.y; tq.z += a0.z; tq.w += a0.w;
                asm volatile("" ::: "memory");
            }

            float4* row = (float4*)(out + (size_t)n * COUT);
            if (lane < 16) row[lane] = tq;          // overwrite pre-zeroed row
        }
    }
}

extern "C" void kernel_launch(void* const* d_in, const int* in_sizes, int n_in,
                              void* d_out, int out_size, void* d_ws, size_t ws_size,
                              hipStream_t stream) {
    const float* query     = (const float*)d_in[0];
    const float* support   = (const float*)d_in[1];
    const int*   neighbors = (const int*)  d_in[2];
    const float* x         = (const float*)d_in[3];
    const float* kpts      = (const float*)d_in[4];
    const float* weight    = (const float*)d_in[5];
    float*       out       = (float*)d_out;

    int*  counts   = (int*)d_ws;
    int2* worklist = (int2*)((char*)d_ws + WL_OFF);

    scan_emit<<<N_Q / 4, 128, 0, stream>>>(
        query, support, neighbors, counts, worklist, (float4*)out);
    close_kernel<<<2048, 256, 0, stream>>>(
        query, support, neighbors, x, kpts, weight, counts, worklist, out);
}

// Round 25
// 27.733 us; speedup vs baseline: 1.5180x; 1.5180x over previous
//
#include <hip/hip_runtime.h>

#define N_Q   50000
#define N_S   50000
#define M_NB  32
#define K_PTS 15
#define CIN   64
#define COUT  64
#define WPB   2
#define THR   0.0101f   // ||nb||^2 bound for any w>0 (exact: 0.009901)

// Event: racc gather of the weighted feature row, then wide GEMV.
// x-row base is hoisted to SGPR (readfirstlane) -> saddr-form vector load.
__device__ __forceinline__ void do_event(
    unsigned em, int laneoff, float w, int idx,
    float* bc, const float* wq, int cg,
    const float* __restrict__ x, int lane, float4& tout)
{
    float racc = 0.f;
    do {
        const int src = laneoff + __builtin_ctz(em); em &= em - 1;
        const float wsrc = __shfl(w, src);
        const int   isrc = __builtin_amdgcn_readfirstlane(__shfl(idx, src));
        racc = fmaf(wsrc, x[(size_t)isrc * CIN + lane], racc);
    } while (em);
    bc[lane] = racc;
    asm volatile("" ::: "memory");
    float4 a0 = make_float4(0.f, 0.f, 0.f, 0.f);
    float4 a1 = make_float4(0.f, 0.f, 0.f, 0.f);
    #pragma unroll
    for (int i = 0; i < 16; i += 2) {
        const float4 v0 = *(const float4*)(wq + (i + 0) * 4 * COUT);
        const float4 v1 = *(const float4*)(wq + (i + 1) * 4 * COUT);
        const float xc0 = bc[cg + 4 * i];
        const float xc1 = bc[cg + 4 * i + 4];
        a0.x = fmaf(xc0, v0.x, a0.x); a0.y = fmaf(xc0, v0.y, a0.y);
        a0.z = fmaf(xc0, v0.z, a0.z); a0.w = fmaf(xc0, v0.w, a0.w);
        a1.x = fmaf(xc1, v1.x, a1.x); a1.y = fmaf(xc1, v1.y, a1.y);
        a1.z = fmaf(xc1, v1.z, a1.z); a1.w = fmaf(xc1, v1.w, a1.w);
    }
    a0.x += a1.x; a0.y += a1.y; a0.z += a1.z; a0.w += a1.w;
    a0.x += __shfl_xor(a0.x, 16); a0.y += __shfl_xor(a0.y, 16);
    a0.z += __shfl_xor(a0.z, 16); a0.w += __shfl_xor(a0.w, 16);
    a0.x += __shfl_xor(a0.x, 32); a0.y += __shfl_xor(a0.y, 32);
    a0.z += __shfl_xor(a0.z, 32); a0.w += __shfl_xor(a0.w, 32);
    tout.x += a0.x; tout.y += a0.y; tout.z += a0.z; tout.w += a0.w;
    asm volatile("" ::: "memory");
}

// Champion (R19, 27.78us): one wave per TWO query points (A = lanes 0-31,
// B = lanes 32-63), scalar-path query loads, single fused dispatch, no
// workspace, no atomics. Sparsity (exact): w[k][m] = max(1 - d/0.05, 0),
// ||kp|| <= 0.0495, so w > 0 requires ||nb||^2 < 0.009901 (0.0101 conserv.).
__global__ __launch_bounds__(128) void kpconv_fused8(
    const float* __restrict__ query,     // [N,3]
    const float* __restrict__ support,   // [N0,3]
    const int*   __restrict__ neighbors, // [N,M]
    const float* __restrict__ x,         // [N0,CIN]
    const float* __restrict__ kpts,      // [K,3]
    const float* __restrict__ weight,    // [K,CIN,COUT]
    float*       __restrict__ out)       // [N,COUT]
{
    __shared__ float s_kx[K_PTS], s_ky[K_PTS], s_kz[K_PTS], s_kk[K_PTS];
    __shared__ float s_bc[WPB][CIN];

    const int tid = threadIdx.x;
    if (tid < K_PTS) {
        float kx = kpts[tid * 3 + 0];
        float ky = kpts[tid * 3 + 1];
        float kz = kpts[tid * 3 + 2];
        s_kx[tid] = kx; s_ky[tid] = ky; s_kz[tid] = kz;
        s_kk[tid] = kx * kx + ky * ky + kz * kz;   // same 3-term fp32 sum as ref
    }
    __syncthreads();

    const int wv   = __builtin_amdgcn_readfirstlane(tid >> 6);  // uniform SGPR
    const int lane = tid & 63;
    const int base = blockIdx.x * (WPB * 2) + wv * 2;
    const int h    = lane >> 5;                    // half: 0 -> A, 1 -> B
    const int n    = base + h;
    const int m    = lane & 31;

    // scalar (SMEM) query loads: uniform addresses
    const float qxA = query[(base + 0) * 3 + 0];
    const float qyA = query[(base + 0) * 3 + 1];
    const float qzA = query[(base + 0) * 3 + 2];
    const float qxB = query[(base + 1) * 3 + 0];
    const float qyB = query[(base + 1) * 3 + 1];
    const float qzB = query[(base + 1) * 3 + 2];
    const float qx = h ? qxB : qxA;                // v_cndmask
    const float qy = h ? qyB : qyA;
    const float qz = h ? qzB : qzA;

    const int idx = neighbors[n * M_NB + m];       // coalesced (2 rows/wave)

    float dx = 0.f, dy = 0.f, dz = 0.f, nn = 1e30f;
    if (idx < N_S) {                               // idx==N_S: shadow, w==0
        dx = support[idx * 3 + 0] - qx;
        dy = support[idx * 3 + 1] - qy;
        dz = support[idx * 3 + 2] - qz;
        nn = dx * dx + dy * dy + dz * dz;
    }

    const int og = (lane & 15) * 4;
    const int cg = lane >> 4;

    float4 toutA = make_float4(0.f, 0.f, 0.f, 0.f);
    float4 toutB = make_float4(0.f, 0.f, 0.f, 0.f);

    if (__ballot(nn < THR)) {                      // ~23% of waves
        for (int k = 0; k < K_PTS; ++k) {
            float w = 0.f;
            if (nn < THR) {
                float dot = dx * s_kx[k] + dy * s_ky[k] + dz * s_kz[k];
                float sq  = fmaxf(nn - 2.f * dot + s_kk[k], 0.f);  // ref expansion
                if (sq < 0.0025f)                   // sqrt(sq) < 0.05 => w > 0
                    w = 1.f - sqrtf(sq) * 20.f;     // 1/0.05 == 20 exactly
            }
            const unsigned long long em = __ballot(w > 0.f);
            if (!em) continue;                      // common: k has no hits

            const float* wq = weight + (size_t)k * CIN * COUT + cg * COUT + og;

            unsigned mm;
            if ((mm = (unsigned)(em & 0xffffffffull)))
                do_event(mm,  0, w, idx, s_bc[wv], wq, cg, x, lane, toutA);
            if ((mm = (unsigned)(em >> 32)))
                do_event(mm, 32, w, idx, s_bc[wv], wq, cg, x, lane, toutB);
        }
    }

    float4* rowA = (float4*)(out + (size_t)(base + 0) * COUT);
    float4* rowB = (float4*)(out + (size_t)(base + 1) * COUT);
    if (lane < 16)       rowA[lane]      = toutA;
    else if (lane < 32)  rowB[lane - 16] = toutB;
}

extern "C" void kernel_launch(void* const* d_in, const int* in_sizes, int n_in,
                              void* d_out, int out_size, void* d_ws, size_t ws_size,
                              hipStream_t stream) {
    const float* query     = (const float*)d_in[0];
    const float* support   = (const float*)d_in[1];
    const int*   neighbors = (const int*)  d_in[2];
    const float* x         = (const float*)d_in[3];
    const float* kpts      = (const float*)d_in[4];
    const float* weight    = (const float*)d_in[5];
    float*       out       = (float*)d_out;

    kpconv_fused8<<<N_Q / 4, 128, 0, stream>>>(    // 12500 blocks, 2 waves
        query, support, neighbors, x, kpts, weight, out);
}